// Round 10
// baseline (272.191 us; speedup 1.0000x reference)
//
#include <hip/hip_runtime.h>

#define NPTS      10000
#define NPTS_PAD  10240          // 80 point-waves x 128 pts (2/lane)
#define NRAYS     4096
#define PGRP      20             // point groups (blocks of 4 waves = 512 pts)
#define RCHUNK    128            // ray chunks
#define RAYS_PC   32             // rays per chunk
#define PT_BLOCKS (NPTS_PAD / 256)   // 40 setup point-blocks
#define NFP       27             // float4 per lane (54 fields / 2)
#define LOG2E     1.44269504f

typedef float v2 __attribute__((ext_vector_type(2)));

// ---- static device scratch ----
// g_T: transposed point data [g:80][fp:27][lane:64] float4
//   float4 = { f_{2fp}(p0), f_{2fp}(p1), f_{2fp+1}(p0), f_{2fp+1}(p1) }
//   fields: 0..2 = x,y,z; 3 = w1 (-delta*LOG2E); 4 = w0 (sigma*opacity);
//           5..52 = sh coeffs (k*3+ch order); 53 = pad
__device__ float4 g_T[80 * NFP * 64];
__device__ float  g_rays[(NRAYS + 2) * 24];  // o(3), d(3), sh*LOG2E(16), pad2
__device__ float  g_acc [NRAYS * 5];         // Sr,Sg,Sb,Sd,S
__device__ float  g_oppart[PT_BLOCKS];

__device__ __forceinline__ float fast_rcp(float x)  { return __builtin_amdgcn_rcpf(x); }
__device__ __forceinline__ float fast_exp2(float x) { return __builtin_amdgcn_exp2f(x); }
__device__ __forceinline__ float fast_sigmoid(float x) { return fast_rcp(1.0f + fast_exp2(-x * LOG2E)); }

__device__ __forceinline__ v2 v2splat(float s) { v2 r; r.x = s; r.y = s; return r; }
__device__ __forceinline__ v2 fmav(v2 a, v2 b, v2 c) { return __builtin_elementwise_fma(a, b, c); }
__device__ __forceinline__ v2 exp2v(v2 a) { v2 r; r.x = fast_exp2(a.x); r.y = fast_exp2(a.y); return r; }
__device__ __forceinline__ v2 rsqv(v2 a)  { v2 r; r.x = __builtin_amdgcn_rsqf(a.x); r.y = __builtin_amdgcn_rsqf(a.y); return r; }
__device__ __forceinline__ v2 rcpv(v2 a)  { v2 r; r.x = fast_rcp(a.x); r.y = fast_rcp(a.y); return r; }
__device__ __forceinline__ v2 f4lo(float4 f) { v2 r; r.x = f.x; r.y = f.y; return r; }
__device__ __forceinline__ v2 f4hi(float4 f) { v2 r; r.x = f.z; r.y = f.w; return r; }

// wave64 sum via DPP (VALU only, no DS pipe). Total lands in lane 63.
template <int CTRL>
__device__ __forceinline__ float dpp_step(float x) {
    return x + __int_as_float(
        __builtin_amdgcn_update_dpp(0, __float_as_int(x), CTRL, 0xf, 0xf, true));
}
__device__ __forceinline__ float wave_sum63(float x) {
    x = dpp_step<0x111>(x);  // row_shr:1
    x = dpp_step<0x112>(x);  // row_shr:2
    x = dpp_step<0x114>(x);  // row_shr:4
    x = dpp_step<0x118>(x);  // row_shr:8  -> lane15 of each row = row sum
    x = dpp_step<0x142>(x);  // row_bcast:15 -> lane31+=sum(16:31) etc.
    x = dpp_step<0x143>(x);  // row_bcast:31 -> lane63 = total
    return x;
}

// ---------------- Kernel 1: merged setup (rays + transposed points) ----------
__global__ __launch_bounds__(256) void setup(const float* __restrict__ ro,
                                             const float* __restrict__ rd,
                                             const float* __restrict__ pos,
                                             const int*   __restrict__ sidx,
                                             const float* __restrict__ log_delta,
                                             const float* __restrict__ log_sigma,
                                             const float* __restrict__ raw_op,
                                             const float* __restrict__ shc) {
    if (blockIdx.x < 16) {
        int r = blockIdx.x * 256 + threadIdx.x;
        float* a = g_acc + (size_t)r * 5;
        a[0] = a[1] = a[2] = a[3] = a[4] = 0.0f;

        float ox = ro[r * 3 + 0], oy = ro[r * 3 + 1], oz = ro[r * 3 + 2];
        float dx = rd[r * 3 + 0], dy = rd[r * 3 + 1], dz = rd[r * 3 + 2];
        float inv = __builtin_amdgcn_rsqf(dx * dx + dy * dy + dz * dz);
        float x = dx * inv, y = dy * inv, z = dz * inv;
        float* o = g_rays + (size_t)r * 24;
        o[0] = ox; o[1] = oy; o[2] = oz;
        o[3] = x;  o[4] = y;  o[5] = z;
        float* sh = o + 6;
        float zz = z * z, xx = x * x, yy = y * y;
        // SH basis prescaled by LOG2E so sigmoid uses exp2 directly
        sh[0]  = LOG2E * 0.282095f;
        sh[1]  = LOG2E * 0.488603f * y;
        sh[2]  = LOG2E * 0.488603f * z;
        sh[3]  = LOG2E * 0.488603f * x;
        sh[4]  = LOG2E * 1.092548f * x * y;
        sh[5]  = LOG2E * 1.092548f * y * z;
        sh[6]  = LOG2E * 0.315392f * (3.0f * zz - 1.0f);
        sh[7]  = LOG2E * 1.092548f * x * z;
        sh[8]  = LOG2E * 0.546274f * (xx - yy);
        sh[9]  = LOG2E * 0.590044f * y * (3.0f * xx - yy);
        sh[10] = LOG2E * 2.890611f * x * y * z;
        sh[11] = LOG2E * 0.457046f * y * (5.0f * zz - 1.0f);
        sh[12] = LOG2E * 0.373176f * z * (5.0f * zz - 3.0f);
        sh[13] = LOG2E * 0.457046f * x * (5.0f * zz - 1.0f);
        sh[14] = LOG2E * 1.445306f * z * (xx - yy);
        sh[15] = LOG2E * 0.590044f * x * (xx - 3.0f * yy);
    } else {
        int pb = blockIdx.x - 16;
        int n  = pb * 256 + threadIdx.x;        // [0, NPTS_PAD)
        int g  = n >> 7;                        // point-wave index
        int l  = (n >> 1) & 63;                 // lane owning this point
        int b  = n & 1;                         // slot within lane pair
        float vals[54];
        float op = 0.0f;
        if (n < NPTS) {
            vals[0] = pos[n * 3 + 0];
            vals[1] = pos[n * 3 + 1];
            vals[2] = pos[n * 3 + 2];
            int s = sidx[n];
            op = fast_sigmoid(raw_op[n]);
            vals[3] = -__expf(log_delta[s]) * LOG2E;
            vals[4] =  __expf(log_sigma[s]) * op;
            const float* src = shc + (size_t)n * 48;
#pragma unroll
            for (int i = 0; i < 48; ++i) vals[5 + i] = src[i];
        } else {
            vals[0] = 1e3f; vals[1] = 1e3f; vals[2] = 1e3f;
            vals[3] = 0.0f; vals[4] = 0.0f;     // w0=0 -> zero contribution
#pragma unroll
            for (int i = 0; i < 48; ++i) vals[5 + i] = 0.0f;
        }
        vals[53] = 0.0f;
        float* T = (float*)g_T;
#pragma unroll
        for (int f = 0; f < 54; ++f)
            T[(size_t)(((g * NFP + (f >> 1)) * 64 + l) * 4 + ((f & 1) << 1) + b)] = vals[f];

        __shared__ float blk;
        if (threadIdx.x == 0) blk = 0.0f;
        __syncthreads();
        float v = op;
#pragma unroll
        for (int off = 32; off > 0; off >>= 1) v += __shfl_down(v, off, 64);
        if ((threadIdx.x & 63) == 0) atomicAdd(&blk, v);
        __syncthreads();
        if (threadIdx.x == 0) g_oppart[pb] = blk;
    }
}

// ---------------- Kernel 2: main — point-resident lanes, rays iterate -------
// SH coeff i (0..47) lives at field 5+i:
#define CF(i) ((((5 + (i)) & 1)) ? f4hi(Q[(5 + (i)) >> 1]) : f4lo(Q[(5 + (i)) >> 1]))

__global__ __launch_bounds__(256, 3) void nerf_main() {
    int pb = blockIdx.x % PGRP;        // point group (4 waves = 512 points)
    int rc = blockIdx.x / PGRP;        // ray chunk
    int wv = threadIdx.x >> 6, lane = threadIdx.x & 63;
    int g  = pb * 4 + wv;              // global point-wave index [0,80)

    // ---- load this lane's 2 points (once): 27 coalesced dwordx4 ----
    float4 Q[NFP];
    {
        const float4* base = g_T + ((size_t)g * NFP * 64) + lane;
#pragma unroll
        for (int fp = 0; fp < NFP; ++fp) Q[fp] = base[fp * 64];
    }
    v2 px = f4lo(Q[0]), py = f4hi(Q[0]);
    v2 pz = f4lo(Q[1]), w1 = f4hi(Q[1]);
    v2 w0 = f4lo(Q[2]);
    const v2 one2 = v2splat(1.0f);

    int r0 = rc * RAYS_PC;
    float A[22], B[22];

#define LOADRAY(dst, rr) {                                   \
        const float* rp_ = g_rays + (size_t)(rr) * 24;       \
        _Pragma("unroll")                                    \
        for (int i_ = 0; i_ < 22; ++i_) dst[i_] = rp_[i_]; }

#define BODY(R, ray) {                                                        \
        v2 rx = px - v2splat(R[0]);                                           \
        v2 ry = py - v2splat(R[1]);                                           \
        v2 rz = pz - v2splat(R[2]);                                           \
        v2 d2 = rx * rx; d2 = fmav(ry, ry, d2); d2 = fmav(rz, rz, d2);        \
        v2 inv = rsqv(d2);                                                    \
        v2 dn = rx * v2splat(R[3]);                                           \
        dn = fmav(ry, v2splat(R[4]), dn);                                     \
        dn = fmav(rz, v2splat(R[5]), dn);                                     \
        v2 t = fmav(-dn, inv, one2);                                          \
        v2 contrib = exp2v(w1 * t * t) * w0 * inv;                            \
        v2 sdist = d2 * inv * contrib;                                        \
        v2 s0 = v2splat(0.0f), s1 = s0, s2 = s0;                              \
        _Pragma("unroll")                                                     \
        for (int k = 0; k < 16; ++k) {                                        \
            v2 shk = v2splat(R[6 + k]);                                       \
            s0 = fmav(CF(3 * k + 0), shk, s0);                                \
            s1 = fmav(CF(3 * k + 1), shk, s1);                                \
            s2 = fmav(CF(3 * k + 2), shk, s2);                                \
        }                                                                     \
        v2 a0 = one2 + exp2v(-s0);                                            \
        v2 a1 = one2 + exp2v(-s1);                                            \
        v2 a2 = one2 + exp2v(-s2);                                            \
        v2 ab = a0 * a1;                                                      \
        v2 CI = contrib * rcpv(ab * a2);                                      \
        v2 vr = CI * (a1 * a2), vg = CI * (a0 * a2), vb = CI * ab;            \
        float hr = wave_sum63(vr.x + vr.y);                                   \
        float hg = wave_sum63(vg.x + vg.y);                                   \
        float hb = wave_sum63(vb.x + vb.y);                                   \
        float hd = wave_sum63(sdist.x + sdist.y);                             \
        float hs = wave_sum63(contrib.x + contrib.y);                         \
        if (lane == 63) {                                                     \
            float* ac = g_acc + (size_t)(ray) * 5;                            \
            atomicAdd(ac + 0, hr); atomicAdd(ac + 1, hg);                     \
            atomicAdd(ac + 2, hb); atomicAdd(ac + 3, hd);                     \
            atomicAdd(ac + 4, hs);                                            \
        }                                                                     \
    }

    LOADRAY(A, r0)
#pragma unroll 1
    for (int j = 0; j < RAYS_PC; j += 2) {
        LOADRAY(B, r0 + j + 1)
        BODY(A, r0 + j)
        LOADRAY(A, r0 + j + 2)          // last iter reads pad rays (harmless)
        BODY(B, r0 + j + 1)
    }
}

// ---------------- Kernel 3: finalize (f32 output) ----------------------------
__global__ void finalize(float* __restrict__ out) {
    int r = blockIdx.x * blockDim.x + threadIdx.x;
    if (r >= NRAYS) return;
    float opv = 0.0f;
#pragma unroll
    for (int i = 0; i < PT_BLOCKS; ++i) opv += g_oppart[i];
    const float* a = g_acc + (size_t)r * 5;
    float inv = fast_rcp(a[4] + 1e-8f);
    out[r * 3 + 0]     = a[0] * inv;
    out[r * 3 + 1]     = a[1] * inv;
    out[r * 3 + 2]     = a[2] * inv;
    out[NRAYS * 3 + r] = a[3] * inv;
    out[NRAYS * 4 + r] = opv * (1.0f / NPTS);
}

extern "C" void kernel_launch(void* const* d_in, const int* in_sizes, int n_in,
                              void* d_out, int out_size, void* d_ws, size_t ws_size,
                              hipStream_t stream) {
    const float* rays_o    = (const float*)d_in[0];
    const float* rays_d    = (const float*)d_in[1];
    const float* positions = (const float*)d_in[2];
    const int*   sidx      = (const int*)d_in[3];
    const float* log_delta = (const float*)d_in[4];
    const float* log_sigma = (const float*)d_in[5];
    const float* raw_op    = (const float*)d_in[6];
    const float* shc       = (const float*)d_in[7];

    setup<<<16 + PT_BLOCKS, 256, 0, stream>>>(
        rays_o, rays_d, positions, sidx, log_delta, log_sigma, raw_op, shc);
    nerf_main<<<PGRP * RCHUNK, 256, 0, stream>>>();
    finalize<<<NRAYS / 256, 256, 0, stream>>>((float*)d_out);
}